// Round 4
// baseline (207.388 us; speedup 1.0000x reference)
//
#include <hip/hip_runtime.h>
#include <stdint.h>

typedef short s16x8 __attribute__((ext_vector_type(8)));
typedef float f32x4 __attribute__((ext_vector_type(4)));
typedef unsigned long long u64;

#define IN_F   256
#define OUT_F  256
#define BATCH  16384
#define NB     31
#define KONE   8192
#define KTOT   8448

typedef const __attribute__((address_space(1))) void* as1cvp;
typedef __attribute__((address_space(3))) void* as3vp;

__device__ __forceinline__ unsigned short f2bf(float f) {
    unsigned u = __float_as_uint(f);
    u += 0x7FFFu + ((u >> 16) & 1u);   // RNE
    return (unsigned short)(u >> 16);
}

// ---------------- kernel 1: fused [out-zero + minmax partials] | build_wb ----
// blocks 0..511: zero 'out' slice (K-split atomics need it) + column min/max
// partials. blocks 512..767: Haar-synthesize Wb. Independent work fused to cut
// serialized launch overhead (~10us/launch was ~half of the 78us prep gap).
__global__ __launch_bounds__(256) void prep1(
    const float* __restrict__ x, const float* __restrict__ bw,
    const float* __restrict__ sw, const float* __restrict__ sc,
    float* __restrict__ pmn, float* __restrict__ pmx,
    unsigned short* __restrict__ Wb, float* __restrict__ outz) {
    const int blk = blockIdx.x, t = threadIdx.x;
    if (blk < 512) {
        float4 z; z.x = z.y = z.z = z.w = 0.f;
        float4* oz = (float4*)outz + (size_t)blk * 2048;
#pragma unroll
        for (int r = 0; r < 8; ++r) oz[t + r * 256] = z;
        const int b0 = blk * 32;
        float mn = 3.4e38f, mx = -3.4e38f;
        for (int r = 0; r < 32; ++r) {
            float v = x[(size_t)(b0 + r) * IN_F + t];
            mn = fminf(mn, v);
            mx = fmaxf(mx, v);
        }
        pmn[blk * 256 + t] = mn;
        pmx[blk * 256 + t] = mx;
    } else {
        const int o = blk - 512, i = t;
        const float s = sc[o * IN_F + i];
        const float* swp = sw + (size_t)(o * IN_F + i) * NB;
        float w[NB];
#pragma unroll
        for (int k = 0; k < NB; ++k) w[k] = swp[k];
        unsigned short* dst = Wb + (size_t)o * KTOT + i * 32;
#pragma unroll
        for (int q = 0; q < 4; ++q) {
            union { s16x8 v; unsigned short s8[8]; } pk;
#pragma unroll
            for (int e = 0; e < 8; ++e) {
                int j = q * 8 + e;
                float acc = 0.f;
#pragma unroll
                for (int l = 0; l < 5; ++l) {
                    int kk = (1 << l) - 1 + (j >> (5 - l));
                    acc += (((j >> (4 - l)) & 1) ? -w[kk] : w[kk]);
                }
                pk.s8[e] = f2bf(acc * s);
            }
            *(s16x8*)(dst + q * 8) = pk.v;
        }
        Wb[(size_t)o * KTOT + KONE + i] = f2bf(bw[o * IN_F + i]);
    }
}

// ---------------- kernel 2: reduce partials, emit xmin & rden ----------------
__global__ __launch_bounds__(64) void minmax_reduce(
    const float* __restrict__ pmn, const float* __restrict__ pmx,
    float* __restrict__ xminF, float* __restrict__ rdenF) {
    const int j = blockIdx.x;
    const int lane = threadIdx.x;
    float mn = 3.4e38f, mx = -3.4e38f;
#pragma unroll
    for (int i = 0; i < 8; ++i) {
        int b = lane * 8 + i;
        mn = fminf(mn, pmn[(size_t)b * 256 + j]);
        mx = fmaxf(mx, pmx[(size_t)b * 256 + j]);
    }
#pragma unroll
    for (int off = 32; off; off >>= 1) {
        mn = fminf(mn, __shfl_down(mn, off));
        mx = fmaxf(mx, __shfl_down(mx, off));
    }
    if (lane == 0) {
        xminF[j] = mn;
        rdenF[j] = 1.0f / (mx - mn + 1e-8f);   // verified chain: rcp-mult
    }
}

// ---------------- kernel 3: leaf indices, natural layout lt[b][i] -----------
__global__ __launch_bounds__(256) void leafk(
    const float* __restrict__ x, const float* __restrict__ xminF,
    const float* __restrict__ rdenF, unsigned char* __restrict__ lt) {
    const int lane = threadIdx.x & 63, w = threadIdx.x >> 6;
    const int b0 = blockIdx.x * 64;
    const float4 mn = *(const float4*)(xminF + lane * 4);
    const float4 rd = *(const float4*)(rdenF + lane * 4);
#pragma unroll 4
    for (int r = 0; r < 16; ++r) {
        int row = b0 + w * 16 + r;
        float4 v = *(const float4*)(x + (size_t)row * IN_F + lane * 4);
        unsigned b[4];
        float xs[4] = {v.x, v.y, v.z, v.w};
        float ms[4] = {mn.x, mn.y, mn.z, mn.w};
        float rs[4] = {rd.x, rd.y, rd.z, rd.w};
#pragma unroll
        for (int e = 0; e < 4; ++e) {
            float xn = (xs[e] - ms[e]) * rs[e];
            int l = (int)(xn * 32.0f);
            b[e] = (l >= 0 && l < 32) ? (unsigned)l : 255u;
        }
        unsigned pk = b[0] | (b[1] << 8) | (b[2] << 16) | (b[3] << 24);
        *(unsigned*)(lt + (size_t)row * IN_F + lane * 4) = pk;
    }
}

// ---------------- kernel 4: BARRIER-FREE one-hot GEMM ------------------------
// Each wave fully independent: M64xN32 tile (mt=4, nt=2 -> per-wave B ds_read
// halved to 4KB/kb), PRIVATE 8KB LDS double-buffer staged by the wave's own
// global_load_lds, synchronized only by counted s_waitcnt vmcnt(4) (T4): the
// stage for kb+1 is issued at loop top into the buffer whose reads completed
// last iteration (program-order anti-dep), so 4-8 loads stay in flight across
// iterations and NO __syncthreads exists. Kills R3's per-kb vmcnt(0) drain +
// lockstep (MfmaUtil pinned at 29%). Frag layouts / swizzle / one-hot synth /
// z-split+atomics byte-identical to the verified R3 math.
__global__ __launch_bounds__(256, 4) void gemm_kan(
    const float* __restrict__ x,
    const unsigned short* __restrict__ Wb,
    const unsigned char* __restrict__ lt,
    float* __restrict__ out)
{
    __shared__ unsigned short Bsh[4][2][2048];   // [wave][dbuf][4KB] = 32KB

    const int t    = threadIdx.x;
    const int lane = t & 63;
    const int wv   = t >> 6;           // 0..3
    const int wm   = wv & 1, wn = wv >> 1;

    // XCD-bijective swizzle: XCD k gets one (ntile,z) slice over all mtiles.
    const int bid   = blockIdx.x;
    const int sid   = (bid & 7) * 128 + (bid >> 3);
    const int mtile = sid & 127;
    const int ntile = (sid >> 7) & 3;
    const int zz    = sid >> 9;
    const int kbeg  = zz ? 68 : 0;
    const int kend  = zz ? 132 : 68;

    const int rr = lane & 15, kq = lane >> 4;
    const int mbase = mtile * 128 + wm * 64;
    const int nb    = ntile * 64 + wn * 32;

    // B glds source (pre-swizzled chunk (lane&7)^(lane>>3), row nb+8q+(lane>>3))
    const unsigned char* bbase = (const unsigned char*)(Wb
        + (size_t)(nb + (lane >> 3)) * KTOT + (((lane & 7) ^ (lane >> 3)) << 3));

    const unsigned char* lp0 = lt + (size_t)(mbase +  0 + rr) * IN_F;
    const unsigned char* lp1 = lt + (size_t)(mbase + 16 + rr) * IN_F;
    const unsigned char* lp2 = lt + (size_t)(mbase + 32 + rr) * IN_F;
    const unsigned char* lp3 = lt + (size_t)(mbase + 48 + rr) * IN_F;

    int boff[2][2];   // [ks][nt] byte offsets within a 4KB buffer
#pragma unroll
    for (int ks = 0; ks < 2; ++ks)
#pragma unroll
        for (int nt = 0; nt < 2; ++nt) {
            int nn = nt * 16 + rr, c = ks * 4 + kq;
            boff[ks][nt] = (nn << 7) + ((c ^ (nn & 7)) << 4);
        }
    const char* bufb[2] = { (const char*)&Bsh[wv][0][0], (const char*)&Bsh[wv][1][0] };

#define STAGE(KB)                                                              \
    {                                                                          \
        const unsigned char* _src = bbase + (size_t)(KB) * 128;                \
        unsigned short* _dst = &Bsh[wv][(KB) & 1][0];                          \
        _Pragma("unroll")                                                      \
        for (int q = 0; q < 4; ++q)                                            \
            __builtin_amdgcn_global_load_lds(                                  \
                (as1cvp)(_src + (size_t)q * 8 * KTOT * 2),                     \
                (as3vp)(uint32_t)(uintptr_t)(_dst + q * 512), 16, 0, 0);       \
    }

    u64 L0 = *(const u64*)(lp0 + 2 * kbeg);
    u64 L1 = *(const u64*)(lp1 + 2 * kbeg);
    u64 L2 = *(const u64*)(lp2 + 2 * kbeg);
    u64 L3 = *(const u64*)(lp3 + 2 * kbeg);
    STAGE(kbeg);

    f32x4 acc[4][2] = {};

    for (int kb0 = kbeg; kb0 < kend; kb0 += 4) {
        // prefetch next leaf group; pin issue point so these stay OLDER than
        // the glds below (FIFO vmcnt: draining to 4 newest then drains these)
        u64 nL0 = L0, nL1 = L1, nL2 = L2, nL3 = L3;
        if (kb0 + 4 < kend && kb0 + 4 < 128) {
            nL0 = *(const u64*)(lp0 + 2 * (kb0 + 4));
            nL1 = *(const u64*)(lp1 + 2 * (kb0 + 4));
            nL2 = *(const u64*)(lp2 + 2 * (kb0 + 4));
            nL3 = *(const u64*)(lp3 + 2 * (kb0 + 4));
            asm volatile("" : "+v"(nL0), "+v"(nL1), "+v"(nL2), "+v"(nL3));
        }
        const bool denseg = (kb0 >= 128);
#pragma unroll
        for (int j = 0; j < 4; ++j) {
            const int kb = kb0 + j;
            if (kb + 1 < kend) {
                STAGE(kb + 1);
                asm volatile("s_waitcnt vmcnt(4)" ::: "memory");  // stage(kb) landed
            } else {
                asm volatile("s_waitcnt vmcnt(0)" ::: "memory");
            }

            // B fragments from private buf[kb&1]
            const char* bb = bufb[kb & 1];
            s16x8 bfr[2][2];
#pragma unroll
            for (int ks = 0; ks < 2; ++ks)
#pragma unroll
                for (int nt = 0; nt < 2; ++nt)
                    bfr[ks][nt] = *(const s16x8*)(bb + boff[ks][nt]);

            // A fragments in registers (verified one-hot identity)
            s16x8 af[2][4];
            if (!denseg) {
#pragma unroll
                for (int ks = 0; ks < 2; ++ks)
#pragma unroll
                    for (int mt = 0; mt < 4; ++mt) {
                        const u64 Lw = (mt == 0) ? L0 : (mt == 1) ? L1 : (mt == 2) ? L2 : L3;
                        const int L = (int)((Lw >> (((j << 1) | ks) << 3)) & 255u);
                        unsigned hot = ((L >> 3) == kq) ? (0x3F80u << ((L & 1) << 4)) : 0u;
                        int slot = (L >> 1) & 3;
                        union { s16x8 v; unsigned u[4]; } a;
                        a.u[0] = (slot == 0) ? hot : 0u;
                        a.u[1] = (slot == 1) ? hot : 0u;
                        a.u[2] = (slot == 2) ? hot : 0u;
                        a.u[3] = (slot == 3) ? hot : 0u;
                        af[ks][mt] = a.v;
                    }
            } else {
                // dense relu(x) tail (kb 128..131, z=1 only)
#pragma unroll
                for (int ks = 0; ks < 2; ++ks)
#pragma unroll
                    for (int mt = 0; mt < 4; ++mt) {
                        const float* xr = x + (size_t)(mbase + mt * 16 + rr) * IN_F
                                            + (kb - 128) * 64 + ks * 32 + kq * 8;
                        union { s16x8 v; unsigned short s8[8]; } a;
#pragma unroll
                        for (int e = 0; e < 8; ++e) a.s8[e] = f2bf(fmaxf(xr[e], 0.0f));
                        af[ks][mt] = a.v;
                    }
            }

            __builtin_amdgcn_s_setprio(1);
#pragma unroll
            for (int ks = 0; ks < 2; ++ks)
#pragma unroll
                for (int mt = 0; mt < 4; ++mt)
#pragma unroll
                    for (int nt = 0; nt < 2; ++nt)
                        acc[mt][nt] = __builtin_amdgcn_mfma_f32_16x16x32_bf16(
                            af[ks][mt], bfr[ks][nt], acc[mt][nt], 0, 0, 0);
            __builtin_amdgcn_s_setprio(0);
        }
        L0 = nL0; L1 = nL1; L2 = nL2; L3 = nL3;
    }

    // epilogue: C/D layout col=lane&15, row=(lane>>4)*4+reg; K-split -> atomicAdd
    const int rq = lane >> 4;
#pragma unroll
    for (int mt = 0; mt < 4; ++mt)
#pragma unroll
        for (int nt = 0; nt < 2; ++nt)
#pragma unroll
            for (int v = 0; v < 4; ++v) {
                int row = mbase + mt * 16 + rq * 4 + v;
                int col = nb + nt * 16 + rr;
                atomicAdd(&out[(size_t)row * OUT_F + col], acc[mt][nt][v]);
            }
#undef STAGE
}

// ---------------- host ----------------
extern "C" void kernel_launch(void* const* d_in, const int* in_sizes, int n_in,
                              void* d_out, int out_size, void* d_ws, size_t ws_size,
                              hipStream_t stream) {
    (void)in_sizes; (void)n_in; (void)out_size; (void)ws_size;
    const float* x  = (const float*)d_in[0];   // [16384,256]
    const float* bw = (const float*)d_in[1];   // [256,256]
    const float* sw = (const float*)d_in[2];   // [256,256,31]
    const float* sc = (const float*)d_in[3];   // [256,256]
    float* out = (float*)d_out;

    char* ws = (char*)d_ws;
    unsigned short* Wb   = (unsigned short*)ws;                 // 4,325,376 B
    unsigned char*  lt   = (unsigned char*)(ws + 4325376);      // 4,194,304 B  [b][i]
    // minmax partials alias the (not-yet-written) lt region
    float* pmn   = (float*)(ws + 4325376);                      // 524,288 B
    float* pmx   = (float*)(ws + 4325376 + 524288);             // 524,288 B
    float* xminF = (float*)(ws + 8519680);                      // 1,024 B
    float* rdenF = (float*)(ws + 8520704);                      // 1,024 B

    prep1<<<768, 256, 0, stream>>>(x, bw, sw, sc, pmn, pmx, Wb, out);
    minmax_reduce<<<256, 64, 0, stream>>>(pmn, pmx, xminF, rdenF);
    leafk<<<256, 256, 0, stream>>>(x, xminF, rdenF, lt);
    gemm_kan<<<1024, 256, 0, stream>>>(x, Wb, lt, out);
}